// Round 4
// baseline (48.664 us; speedup 1.0000x reference)
//
#include <hip/hip_runtime.h>
#include <hip/hip_fp16.h>

// SparseActivationEnforcer: keep top-2 (by fp16 |.|, stable ties) of each
// group of 4 along H, zero the rest; row 0 (the "head") copies through.
// x: (1, 8192, 4096) fp32 -> out same shape fp32.
//
// R1: 45.5us = 5.90 TB/s (268 MB HBM round trip). R3: nt-store neutral ->
// Infinity Cache is memory-side, not bypassable; traffic floor is structural.
// R4: nt on BOTH streams (zero intra-dispatch reuse -> don't allocate in L2),
// grid 4096 for finer balance. Target the 6.29 TB/s copy ceiling (~43us).

typedef float f32x4 __attribute__((ext_vector_type(4)));

__global__ __launch_bounds__(256) void sparse_enforce_kernel(
    const f32x4* __restrict__ x, f32x4* __restrict__ out, int ngroups) {
  const int stride = gridDim.x * blockDim.x;
  for (int i = blockIdx.x * blockDim.x + threadIdx.x; i < ngroups; i += stride) {
    f32x4 v = __builtin_nontemporal_load(&x[i]);
    // First row of S (8192 rows x 4096 cols): groups 0..1023 pass through.
    if (i >= 1024) {
      // fp16 abs as ordered unsigned bits (no NaN in N(0,1) inputs).
      const unsigned short a0 = __half_as_ushort(__float2half(v.x)) & 0x7fffu;
      const unsigned short a1 = __half_as_ushort(__float2half(v.y)) & 0x7fffu;
      const unsigned short a2 = __half_as_ushort(__float2half(v.z)) & 0x7fffu;
      const unsigned short a3 = __half_as_ushort(__float2half(v.w)) & 0x7fffu;
      // rank_i = #{j: a_j > a_i} + #{j<i: a_j == a_i}
      //        = sum_{j<i} (a_j >= a_i) + sum_{j>i} (a_j > a_i)
      const int r0 = (a1 > a0) + (a2 > a0) + (a3 > a0);
      const int r1 = (a0 >= a1) + (a2 > a1) + (a3 > a1);
      const int r2 = (a0 >= a2) + (a1 >= a2) + (a3 > a2);
      const int r3 = (a0 >= a3) + (a1 >= a3) + (a2 >= a3);
      // keep iff rank < 2 AND nonzero after fp16 cast (abs bits != 0).
      v.x = (r0 < 2 && a0 != 0u) ? v.x : 0.0f;
      v.y = (r1 < 2 && a1 != 0u) ? v.y : 0.0f;
      v.z = (r2 < 2 && a2 != 0u) ? v.z : 0.0f;
      v.w = (r3 < 2 && a3 != 0u) ? v.w : 0.0f;
    }
    __builtin_nontemporal_store(v, &out[i]);
  }
}

extern "C" void kernel_launch(void* const* d_in, const int* in_sizes, int n_in,
                              void* d_out, int out_size, void* d_ws, size_t ws_size,
                              hipStream_t stream) {
  const f32x4* x = (const f32x4*)d_in[0];
  f32x4* out = (f32x4*)d_out;
  const int ngroups = in_sizes[0] / 4;  // 8192*4096/4 = 8,388,608
  const int block = 256;
  int grid = (ngroups + block - 1) / block;
  if (grid > 4096) grid = 4096;  // 16 blocks/CU worth of slots; 8 iters/thread
  sparse_enforce_kernel<<<grid, block, 0, stream>>>(x, out, ngroups);
}

// Round 5
// 44.942 us; speedup vs baseline: 1.0828x; 1.0828x over previous
//
#include <hip/hip_runtime.h>
#include <hip/hip_fp16.h>

// SparseActivationEnforcer: keep top-2 (by fp16 |.|, stable ties) of each
// group of 4 along H, zero the rest; row 0 (the "head") copies through.
// x: (1, 8192, 4096) fp32 -> out same shape fp32.
//
// Final config = R1: plain cached load/store, float4/lane, grid 2048.
// Ladder: R1 45.5us (5.90 TB/s, 94% of 6.29 TB/s copy ceiling);
// R3 nt-store neutral (Infinity Cache is memory-side, not bypassable);
// R4 nt-load + grid 4096 regressed to 48.7us. Cache-control bits are a
// dead end; 268 MB HBM round-trip is the structural floor.

typedef float f32x4 __attribute__((ext_vector_type(4)));

__global__ __launch_bounds__(256) void sparse_enforce_kernel(
    const f32x4* __restrict__ x, f32x4* __restrict__ out, int ngroups) {
  const int stride = gridDim.x * blockDim.x;
  for (int i = blockIdx.x * blockDim.x + threadIdx.x; i < ngroups; i += stride) {
    f32x4 v = x[i];
    // First row of S (8192 rows x 4096 cols): groups 0..1023 pass through.
    if (i >= 1024) {
      // fp16 abs as ordered unsigned bits (no NaN in N(0,1) inputs).
      const unsigned short a0 = __half_as_ushort(__float2half(v.x)) & 0x7fffu;
      const unsigned short a1 = __half_as_ushort(__float2half(v.y)) & 0x7fffu;
      const unsigned short a2 = __half_as_ushort(__float2half(v.z)) & 0x7fffu;
      const unsigned short a3 = __half_as_ushort(__float2half(v.w)) & 0x7fffu;
      // rank_i = #{j: a_j > a_i} + #{j<i: a_j == a_i}
      //        = sum_{j<i} (a_j >= a_i) + sum_{j>i} (a_j > a_i)
      const int r0 = (a1 > a0) + (a2 > a0) + (a3 > a0);
      const int r1 = (a0 >= a1) + (a2 > a1) + (a3 > a1);
      const int r2 = (a0 >= a2) + (a1 >= a2) + (a3 > a2);
      const int r3 = (a0 >= a3) + (a1 >= a3) + (a2 >= a3);
      // keep iff rank < 2 AND nonzero after fp16 cast (abs bits != 0).
      v.x = (r0 < 2 && a0 != 0u) ? v.x : 0.0f;
      v.y = (r1 < 2 && a1 != 0u) ? v.y : 0.0f;
      v.z = (r2 < 2 && a2 != 0u) ? v.z : 0.0f;
      v.w = (r3 < 2 && a3 != 0u) ? v.w : 0.0f;
    }
    out[i] = v;
  }
}

extern "C" void kernel_launch(void* const* d_in, const int* in_sizes, int n_in,
                              void* d_out, int out_size, void* d_ws, size_t ws_size,
                              hipStream_t stream) {
  const f32x4* x = (const f32x4*)d_in[0];
  f32x4* out = (f32x4*)d_out;
  const int ngroups = in_sizes[0] / 4;  // 8192*4096/4 = 8,388,608
  const int block = 256;
  int grid = (ngroups + block - 1) / block;
  if (grid > 2048) grid = 2048;  // 8 blocks/CU, grid-stride 16 iters/thread
  sparse_enforce_kernel<<<grid, block, 0, stream>>>(x, out, ngroups);
}